// Round 1
// baseline (1024.037 us; speedup 1.0000x reference)
//
#include <hip/hip_runtime.h>
#include <hip/hip_bf16.h>

// Problem: i_in[post[s]] += weights[s] * (inputs_t[0][pre[s]] > 0)
//   N_SYN = 30,000,000 synapses, N_POST = 200,000 outputs, N_SOURCE = 17,400.
// indices is (N_SYN, 2) int32 rows [post, pre]; weights float32; output float32.
//
// Memory-bound scatter: 360 MB mandatory reads (indices + weights); the 69.6 KB
// activity table is cache-resident; 800 KB output accumulated via L2 float atomics.
// 4 synapses per thread -> int4 x2 + float4 vector loads (fully coalesced).

__global__ __launch_bounds__(256) void syn_scatter_kernel(
    const int* __restrict__ act,        // inputs_t[0], N_SOURCE int32 (0/1)
    const int4* __restrict__ idx4,      // indices viewed as int4: 2 synapses per int4
    const float4* __restrict__ w4,      // weights viewed as float4: 4 synapses
    float* __restrict__ out,
    int n_vec)                          // N_SYN / 4
{
    int t = blockIdx.x * blockDim.x + threadIdx.x;
    if (t >= n_vec) return;

    int4   ia = idx4[2 * t];        // syn0: (post=ia.x, pre=ia.y), syn1: (post=ia.z, pre=ia.w)
    int4   ib = idx4[2 * t + 1];    // syn2: (post=ib.x, pre=ib.y), syn3: (post=ib.z, pre=ib.w)
    float4 wv = w4[t];

    // Gather activity (cache-resident table), predicate the atomic so ~50%
    // of synapses (inactive sources) generate no L2 atomic traffic at all.
    if (act[ia.y] > 0) atomicAdd(&out[ia.x], wv.x);
    if (act[ia.w] > 0) atomicAdd(&out[ia.z], wv.y);
    if (act[ib.y] > 0) atomicAdd(&out[ib.x], wv.z);
    if (act[ib.w] > 0) atomicAdd(&out[ib.z], wv.w);
}

extern "C" void kernel_launch(void* const* d_in, const int* in_sizes, int n_in,
                              void* d_out, int out_size, void* d_ws, size_t ws_size,
                              hipStream_t stream) {
    const int*   inputs_t = (const int*)d_in[0];   // (1, 17400) int32
    const int*   indices  = (const int*)d_in[1];   // (30M, 2) int32
    const float* weights  = (const float*)d_in[2]; // (30M,) float32
    // d_in[3] = n_post scalar; out_size == n_post == 200000

    const int n_syn = in_sizes[2];                 // 30,000,000
    const int n_vec = n_syn / 4;                   // divisible: 7,500,000

    // Harness poisons d_out to 0xAA before every launch — zero it first.
    hipMemsetAsync(d_out, 0, (size_t)out_size * sizeof(float), stream);

    const int block = 256;
    const int grid  = (n_vec + block - 1) / block;
    syn_scatter_kernel<<<grid, block, 0, stream>>>(
        inputs_t,
        (const int4*)indices,
        (const float4*)weights,
        (float*)d_out,
        n_vec);
}